// Round 1
// 507.663 us; speedup vs baseline: 1.1392x; 1.1392x over previous
//
#include <hip/hip_runtime.h>

// Laplacian pyramid build: im (16,3,1024,1024) fp32, levels=5. P = 48 planes.
// Pass 1: gpyr[l+1] = reduce(gpyr[l]) written into out slice l+1 (slice 4 == lpyr[4]).
// Pass 2: slice_l = gpyr[l] - expand(slice_{l+1}), in place (increasing l).

// ---------------- reduce: 5x5 binomial, stride 2, edge clamp ----------------
// Register-blocked, LDS-free. Block (64,4); each thread computes a 4x4 output
// tile (256x16 outputs per block). Per input row: 4 aligned float4 loads cover
// the 11-col stride-2 footprint of 4 output columns; horizontal 5-tap sums are
// built once per row and accumulated into the 4 output rows with compile-time
// folded weights (full unroll). Edge columns (first/last thread of each image
// row only) take a scalar clamped path.
#define RBX 64
#define RBY 4

template <bool EDGE>
__device__ __forceinline__ void reduce_accum(const float* __restrict__ src,
                                             int Hin, int Win, int rbase, int cb,
                                             float (&acc)[4][4]) {
    const float w0 = 0.0625f, w1 = 0.25f, w2 = 0.375f;
    const float wr[5] = {w0, w1, w2, w1, w0};
#pragma unroll
    for (int rr = 0; rr < 11; ++rr) {
        int gr = rbase + rr;
        gr = gr < 0 ? 0 : (gr > Hin - 1 ? Hin - 1 : gr);
        const float* row = src + (size_t)gr * Win;
        float v[16];
        if (!EDGE) {
#pragma unroll
            for (int q = 0; q < 4; ++q) {
                float4 f = *reinterpret_cast<const float4*>(row + cb + 4 * q);
                v[4 * q + 0] = f.x; v[4 * q + 1] = f.y;
                v[4 * q + 2] = f.z; v[4 * q + 3] = f.w;
            }
        } else {
#pragma unroll
            for (int c = 0; c < 16; ++c) {
                int gc = cb + c;
                gc = gc < 0 ? 0 : (gc > Win - 1 ? Win - 1 : gc);
                v[c] = row[gc];
            }
        }
        // horizontal 5-tap at output col c: input cols center-2..center+2 = v[2+2c .. 6+2c]
        float h[4];
#pragma unroll
        for (int c = 0; c < 4; ++c) {
            const float* vv = v + 2 + 2 * c;
            float s04 = vv[0] + vv[4];
            float s13 = vv[1] + vv[3];
            float hh = w0 * s04;
            hh = fmaf(w1, s13, hh);
            hh = fmaf(w2, vv[2], hh);
            h[c] = hh;
        }
        // vertical: output row i uses input rows rbase+2i .. rbase+2i+4
#pragma unroll
        for (int i = 0; i < 4; ++i) {
            const int a = rr - 2 * i;
            if (a >= 0 && a <= 4) {
                const float w = wr[a];
#pragma unroll
                for (int c = 0; c < 4; ++c)
                    acc[i][c] = fmaf(w, h[c], acc[i][c]);
            }
        }
    }
}

__launch_bounds__(256)
__global__ void reduce_kernel(const float* __restrict__ in, float* __restrict__ out,
                              int Hin, int Win, int Hout, int Wout) {
    const int p = blockIdx.z;
    const int t = blockIdx.x * RBX + threadIdx.x;          // output col group: j0 = 4t
    const int i0 = (blockIdx.y * RBY + threadIdx.y) * 4;   // first output row
    const int j0 = 4 * t;
    if (j0 >= Wout || i0 >= Hout) return;

    const float* src = in + (size_t)p * Hin * Win;
    const int cb = 8 * t - 4;        // first loaded input col (16B aligned)
    const int rbase = 2 * i0 - 2;    // first needed input row
    const bool edge = (cb < 0) | (cb + 15 > Win - 1);

    float acc[4][4];
#pragma unroll
    for (int i = 0; i < 4; ++i)
#pragma unroll
        for (int c = 0; c < 4; ++c) acc[i][c] = 0.f;

    if (!edge) reduce_accum<false>(src, Hin, Win, rbase, cb, acc);
    else       reduce_accum<true>(src, Hin, Win, rbase, cb, acc);

    float* drow = out + (size_t)p * Hout * Wout + j0;
#pragma unroll
    for (int i = 0; i < 4; ++i) {
        *reinterpret_cast<float4*>(drow + (size_t)(i0 + i) * Wout) =
            make_float4(acc[i][0], acc[i][1], acc[i][2], acc[i][3]);
    }
}

// ------------- lpyr[l] = fine - expand(coarse); thread per 2 coarse cols -------------
// Even output row (2i): coarse rows (i-1,i,i+1) w (0.125,0.75,0.125)
// Odd  output row (2i+1): coarse rows (i,i+1)   w (0.5,0.5); same in columns.
// Each thread covers coarse cols {2t,2t+1} -> fine cols 4t..4t+3, rows 2i,2i+1:
// fine load + out store are float4 (16 B/lane).
__launch_bounds__(256)
__global__ void lap_kernel(const float* __restrict__ fine, const float* __restrict__ coarse,
                           float* __restrict__ out, int Hc, int Wc) {
    const int t = blockIdx.x * blockDim.x + threadIdx.x;  // coarse col-pair index
    const int i = blockIdx.y * blockDim.y + threadIdx.y;  // coarse row
    const int p = blockIdx.z;
    const int Wc2 = Wc >> 1;
    if (i >= Hc || t >= Wc2) return;

    const float* g = coarse + (size_t)p * Hc * Wc;
    const int im1 = i > 0 ? i - 1 : 0;
    const int ip1 = i < Hc - 1 ? i + 1 : Hc - 1;
    const float* rm = g + (size_t)im1 * Wc;
    const float* r0 = g + (size_t)i   * Wc;
    const float* rp = g + (size_t)ip1 * Wc;

    const int jl = 2 * t - 1 > 0 ? 2 * t - 1 : 0;             // clamp(2t-1)
    const int jr = 2 * t + 2 < Wc - 1 ? 2 * t + 2 : Wc - 1;   // clamp(2t+2)

    // coarse cols 2t-1, 2t, 2t+1, 2t+2 for three rows
    float cm[4], c0[4], cp[4];
    {
        float2 m = *(const float2*)(rm + 2 * t);
        float2 z = *(const float2*)(r0 + 2 * t);
        float2 q = *(const float2*)(rp + 2 * t);
        cm[1] = m.x; cm[2] = m.y;
        c0[1] = z.x; c0[2] = z.y;
        cp[1] = q.x; cp[2] = q.y;
        cm[0] = rm[jl]; cm[3] = rm[jr];
        c0[0] = r0[jl]; c0[3] = r0[jr];
        cp[0] = rp[jl]; cp[3] = rp[jr];
    }

    float e[4], o[4];
#pragma unroll
    for (int c = 0; c < 4; ++c) {
        e[c] = fmaf(0.125f, cm[c], fmaf(0.75f, c0[c], 0.125f * cp[c]));
        o[c] = 0.5f * (c0[c] + cp[c]);
    }

    // horizontal combine: out cols 4t..4t+3
    float ev0 = fmaf(0.125f, e[0], fmaf(0.75f, e[1], 0.125f * e[2]));
    float ev1 = 0.5f * (e[1] + e[2]);
    float ev2 = fmaf(0.125f, e[1], fmaf(0.75f, e[2], 0.125f * e[3]));
    float ev3 = 0.5f * (e[2] + e[3]);
    float od0 = fmaf(0.125f, o[0], fmaf(0.75f, o[1], 0.125f * o[2]));
    float od1 = 0.5f * (o[1] + o[2]);
    float od2 = fmaf(0.125f, o[1], fmaf(0.75f, o[2], 0.125f * o[3]));
    float od3 = 0.5f * (o[2] + o[3]);

    const int Wf = 2 * Wc;
    const size_t fbase = (size_t)p * (size_t)(2 * Hc) * Wf;
    const float4* f0 = (const float4*)(fine + fbase + (size_t)(2 * i) * Wf);
    const float4* f1 = (const float4*)(fine + fbase + (size_t)(2 * i + 1) * Wf);
    float4 a = f0[t], b = f1[t];

    float4* w0p = (float4*)(out + fbase + (size_t)(2 * i) * Wf);
    float4* w1p = (float4*)(out + fbase + (size_t)(2 * i + 1) * Wf);
    w0p[t] = make_float4(a.x - ev0, a.y - ev1, a.z - ev2, a.w - ev3);
    w1p[t] = make_float4(b.x - od0, b.y - od1, b.z - od2, b.w - od3);
}

extern "C" void kernel_launch(void* const* d_in, const int* in_sizes, int n_in,
                              void* d_out, int out_size, void* d_ws, size_t ws_size,
                              hipStream_t stream) {
    (void)in_sizes; (void)n_in; (void)d_ws; (void)ws_size; (void)out_size;
    const float* im = (const float*)d_in[0];
    float* out = (float*)d_out;

    const int P = 48;           // 16 * 3 planes
    const int H0 = 1024, W0 = 1024;

    size_t off[5];
    size_t acc = 0;
    for (int l = 0; l < 5; ++l) {
        off[l] = acc;
        int h = H0 >> l, w = W0 >> l;
        acc += (size_t)P * h * w;
    }

    // Pass 1: reduce chain -> slices 1..4 hold gpyr[1..4]
    for (int l = 0; l < 4; ++l) {
        int Hin = H0 >> l, Win = W0 >> l;
        int Hout = Hin >> 1, Wout = Win >> 1;
        const float* src = (l == 0) ? im : (out + off[l]);
        float* dst = out + off[l + 1];
        dim3 blk(RBX, RBY, 1);
        dim3 grid((Wout + 4 * RBX - 1) / (4 * RBX), (Hout + 4 * RBY - 1) / (4 * RBY), P);
        reduce_kernel<<<grid, blk, 0, stream>>>(src, dst, Hin, Win, Hout, Wout);
    }

    // Pass 2: laplacian levels 0..3 (increasing l so gpyr[l+1] is intact)
    for (int l = 0; l < 4; ++l) {
        int Hc = H0 >> (l + 1), Wc = W0 >> (l + 1);
        const float* fine = (l == 0) ? im : (out + off[l]);
        const float* coarse = out + off[l + 1];
        float* dst = out + off[l];
        dim3 blk(64, 4, 1);
        dim3 grid((Wc / 2 + 63) / 64, (Hc + 3) / 4, P);
        lap_kernel<<<grid, blk, 0, stream>>>(fine, coarse, dst, Hc, Wc);
    }
}

// Round 3
// 487.612 us; speedup vs baseline: 1.1860x; 1.0411x over previous
//
#include <hip/hip_runtime.h>

// Laplacian pyramid build: im (16,3,1024,1024) fp32, levels=5. P = 48 planes.
// Launch plan (5 dispatches):
//   reduce0:  gpyr1 = reduce(im)            -> slice 1
//   fused l=0: lap0 (im, s1 -> s0)   + reduce1 (s1 -> s2)
//   fused l=1: lap1 (s1, s2 -> s1)   + reduce2 (s2 -> s3)
//   fused l=2: lap2 (s2, s3 -> s2)   + reduce3 (s3 -> s4)
//   lap3:      s3 = s3 - expand(s4)
// lap(l) and reduce(l+1) both depend only on gpyr[l+1], write disjoint slices.

#define RBX 64
#define RBY 4

typedef float fx4 __attribute__((ext_vector_type(4)));  // native vec for NT builtins

// ---------------- reduce: 5x5 binomial, stride 2, edge clamp ----------------
// Register-blocked, LDS-free. Each thread computes a 4x4 output tile.
template <bool EDGE>
__device__ __forceinline__ void reduce_accum(const float* __restrict__ src,
                                             int Hin, int Win, int rbase, int cb,
                                             float (&acc)[4][4]) {
    const float w0 = 0.0625f, w1 = 0.25f, w2 = 0.375f;
    const float wr[5] = {w0, w1, w2, w1, w0};
#pragma unroll
    for (int rr = 0; rr < 11; ++rr) {
        int gr = rbase + rr;
        gr = gr < 0 ? 0 : (gr > Hin - 1 ? Hin - 1 : gr);
        const float* row = src + (size_t)gr * Win;
        float v[16];
        if (!EDGE) {
#pragma unroll
            for (int q = 0; q < 4; ++q) {
                fx4 f = *reinterpret_cast<const fx4*>(row + cb + 4 * q);
                v[4 * q + 0] = f.x; v[4 * q + 1] = f.y;
                v[4 * q + 2] = f.z; v[4 * q + 3] = f.w;
            }
        } else {
#pragma unroll
            for (int c = 0; c < 16; ++c) {
                int gc = cb + c;
                gc = gc < 0 ? 0 : (gc > Win - 1 ? Win - 1 : gc);
                v[c] = row[gc];
            }
        }
        float h[4];
#pragma unroll
        for (int c = 0; c < 4; ++c) {
            const float* vv = v + 2 + 2 * c;
            float s04 = vv[0] + vv[4];
            float s13 = vv[1] + vv[3];
            float hh = w0 * s04;
            hh = fmaf(w1, s13, hh);
            hh = fmaf(w2, vv[2], hh);
            h[c] = hh;
        }
#pragma unroll
        for (int i = 0; i < 4; ++i) {
            const int a = rr - 2 * i;
            if (a >= 0 && a <= 4) {
                const float w = wr[a];
#pragma unroll
                for (int c = 0; c < 4; ++c)
                    acc[i][c] = fmaf(w, h[c], acc[i][c]);
            }
        }
    }
}

__device__ __forceinline__ void reduce_block(const float* __restrict__ src,
                                             float* __restrict__ dst,
                                             int Hin, int Win, int Hout, int Wout,
                                             int bx, int by, int tx, int ty) {
    const int t = bx * RBX + tx;          // output col group: j0 = 4t
    const int i0 = (by * RBY + ty) * 4;   // first output row
    const int j0 = 4 * t;
    if (j0 >= Wout || i0 >= Hout) return;

    const int cb = 8 * t - 4;        // first loaded input col (16B aligned)
    const int rbase = 2 * i0 - 2;    // first needed input row
    const bool edge = (cb < 0) | (cb + 15 > Win - 1);

    float acc[4][4];
#pragma unroll
    for (int i = 0; i < 4; ++i)
#pragma unroll
        for (int c = 0; c < 4; ++c) acc[i][c] = 0.f;

    if (!edge) reduce_accum<false>(src, Hin, Win, rbase, cb, acc);
    else       reduce_accum<true>(src, Hin, Win, rbase, cb, acc);

    float* drow = dst + j0;
#pragma unroll
    for (int i = 0; i < 4; ++i) {
        fx4 o = {acc[i][0], acc[i][1], acc[i][2], acc[i][3]};
        *reinterpret_cast<fx4*>(drow + (size_t)(i0 + i) * Wout) = o;
    }
}

__launch_bounds__(256)
__global__ void reduce_kernel(const float* __restrict__ in, float* __restrict__ out,
                              int Hin, int Win, int Hout, int Wout) {
    const int p = blockIdx.z;
    reduce_block(in + (size_t)p * Hin * Win, out + (size_t)p * Hout * Wout,
                 Hin, Win, Hout, Wout, blockIdx.x, blockIdx.y, threadIdx.x, threadIdx.y);
}

// ------------- lap: lpyr[l] = fine - expand(coarse) -------------
// 4 coarse cols / thread -> fine cols 8t..8t+7, rows 2i,2i+1 (16 outputs).
// Per coarse row: 1 aligned float4 + 2 clamped scalars. Fine I/O is float4.
// Even fine row (2i): coarse rows (i-1,i,i+1) w (0.125,0.75,0.125)
// Odd  fine row (2i+1): coarse rows (i,i+1)   w (0.5,0.5); same weights in cols.
template <bool NT>
__device__ __forceinline__ fx4 ld4(const float* p) {
    if (NT) return __builtin_nontemporal_load(reinterpret_cast<const fx4*>(p));
    return *reinterpret_cast<const fx4*>(p);
}
template <bool NT>
__device__ __forceinline__ void st4(float* p, fx4 v) {
    if (NT) __builtin_nontemporal_store(v, reinterpret_cast<fx4*>(p));
    else    *reinterpret_cast<fx4*>(p) = v;
}

template <bool NT>
__device__ __forceinline__ void lap_block(const float* __restrict__ fine,
                                          const float* __restrict__ coarse,
                                          float* __restrict__ out,
                                          int Hc, int Wc, int bx, int by, int tx, int ty) {
    const int t = bx * 64 + tx;      // coarse col quad: cols 4t..4t+3
    const int i = by * 4 + ty;       // coarse row
    if (i >= Hc || t >= (Wc >> 2)) return;

    const int im1 = i > 0 ? i - 1 : 0;
    const int ip1 = i < Hc - 1 ? i + 1 : Hc - 1;
    const float* rm = coarse + (size_t)im1 * Wc;
    const float* r0 = coarse + (size_t)i   * Wc;
    const float* rp = coarse + (size_t)ip1 * Wc;

    const int jl = 4 * t - 1 > 0 ? 4 * t - 1 : 0;             // clamp(4t-1)
    const int jr = 4 * t + 4 < Wc - 1 ? 4 * t + 4 : Wc - 1;   // clamp(4t+4)

    // coarse cols 4t-1 .. 4t+4 for three rows
    float cm[6], c0[6], cp[6];
    {
        fx4 m = *reinterpret_cast<const fx4*>(rm + 4 * t);
        fx4 z = *reinterpret_cast<const fx4*>(r0 + 4 * t);
        fx4 q = *reinterpret_cast<const fx4*>(rp + 4 * t);
        cm[1] = m.x; cm[2] = m.y; cm[3] = m.z; cm[4] = m.w;
        c0[1] = z.x; c0[2] = z.y; c0[3] = z.z; c0[4] = z.w;
        cp[1] = q.x; cp[2] = q.y; cp[3] = q.z; cp[4] = q.w;
        cm[0] = rm[jl]; cm[5] = rm[jr];
        c0[0] = r0[jl]; c0[5] = r0[jr];
        cp[0] = rp[jl]; cp[5] = rp[jr];
    }

    // vertical combine
    float e[6], o[6];
#pragma unroll
    for (int c = 0; c < 6; ++c) {
        e[c] = fmaf(0.125f, cm[c], fmaf(0.75f, c0[c], 0.125f * cp[c]));
        o[c] = 0.5f * (c0[c] + cp[c]);
    }

    // horizontal combine: fine cols 8t..8t+7 (e[1] == coarse col 4t)
    float ev[8], ov[8];
#pragma unroll
    for (int q = 0; q < 4; ++q) {
        ev[2 * q]     = fmaf(0.125f, e[q], fmaf(0.75f, e[q + 1], 0.125f * e[q + 2]));
        ev[2 * q + 1] = 0.5f * (e[q + 1] + e[q + 2]);
        ov[2 * q]     = fmaf(0.125f, o[q], fmaf(0.75f, o[q + 1], 0.125f * o[q + 2]));
        ov[2 * q + 1] = 0.5f * (o[q + 1] + o[q + 2]);
    }

    const int Wf = 2 * Wc;
    const size_t r0off = (size_t)(2 * i) * Wf + 8 * t;
    const float* f0 = fine + r0off;
    const float* f1 = f0 + Wf;
    fx4 a0 = ld4<NT>(f0), a1 = ld4<NT>(f0 + 4);
    fx4 b0 = ld4<NT>(f1), b1 = ld4<NT>(f1 + 4);

    float* w0 = out + r0off;
    float* w1 = w0 + Wf;
    fx4 o0 = {a0.x - ev[0], a0.y - ev[1], a0.z - ev[2], a0.w - ev[3]};
    fx4 o1 = {a1.x - ev[4], a1.y - ev[5], a1.z - ev[6], a1.w - ev[7]};
    fx4 o2 = {b0.x - ov[0], b0.y - ov[1], b0.z - ov[2], b0.w - ov[3]};
    fx4 o3 = {b1.x - ov[4], b1.y - ov[5], b1.z - ov[6], b1.w - ov[7]};
    st4<NT>(w0,     o0);
    st4<NT>(w0 + 4, o1);
    st4<NT>(w1,     o2);
    st4<NT>(w1 + 4, o3);
}

__launch_bounds__(256)
__global__ void lap_kernel(const float* __restrict__ fine, const float* __restrict__ coarse,
                           float* __restrict__ out, int Hc, int Wc) {
    const int p = blockIdx.z;
    const size_t mplane = (size_t)Hc * Wc;
    lap_block<false>(fine + (size_t)p * 4 * mplane, coarse + (size_t)p * mplane,
                     out + (size_t)p * 4 * mplane, Hc, Wc,
                     blockIdx.x, blockIdx.y, threadIdx.x, threadIdx.y);
}

// ------------- fused: lap(l) on y < ylap, reduce(l+1) on y >= ylap -------------
template <bool NT>
__launch_bounds__(256)
__global__ void fused_kernel(const float* __restrict__ fine, const float* __restrict__ mid,
                             float* __restrict__ lap_dst, float* __restrict__ red_dst,
                             int Hc, int Wc, int ylap) {
    const int p = blockIdx.z;
    const size_t mplane = (size_t)Hc * Wc;
    if ((int)blockIdx.y < ylap) {
        lap_block<NT>(fine + (size_t)p * 4 * mplane, mid + (size_t)p * mplane,
                      lap_dst + (size_t)p * 4 * mplane, Hc, Wc,
                      blockIdx.x, blockIdx.y, threadIdx.x, threadIdx.y);
    } else {
        reduce_block(mid + (size_t)p * mplane, red_dst + (size_t)p * (mplane >> 2),
                     Hc, Wc, Hc >> 1, Wc >> 1,
                     blockIdx.x, (int)blockIdx.y - ylap, threadIdx.x, threadIdx.y);
    }
}

extern "C" void kernel_launch(void* const* d_in, const int* in_sizes, int n_in,
                              void* d_out, int out_size, void* d_ws, size_t ws_size,
                              hipStream_t stream) {
    (void)in_sizes; (void)n_in; (void)d_ws; (void)ws_size; (void)out_size;
    const float* im = (const float*)d_in[0];
    float* out = (float*)d_out;

    const int P = 48;           // 16 * 3 planes
    const int H0 = 1024, W0 = 1024;

    size_t off[5];
    size_t acc = 0;
    for (int l = 0; l < 5; ++l) {
        off[l] = acc;
        int h = H0 >> l, w = W0 >> l;
        acc += (size_t)P * h * w;
    }

    // reduce0: im -> slice 1
    {
        int Hout = H0 >> 1, Wout = W0 >> 1;
        dim3 blk(RBX, RBY, 1);
        dim3 grid((Wout + 255) / 256, (Hout + 15) / 16, P);
        reduce_kernel<<<grid, blk, 0, stream>>>(im, out + off[1], H0, W0, Hout, Wout);
    }

    // fused levels l = 0,1,2: lap(l) + reduce(l+1)
    for (int l = 0; l < 3; ++l) {
        int Hc = H0 >> (l + 1), Wc = W0 >> (l + 1);
        int xlap = (Wc / 4 + 63) / 64, ylap = (Hc + 3) / 4;
        int Hout = Hc >> 1, Wout = Wc >> 1;
        int xred = (Wout + 255) / 256, yred = (Hout + 15) / 16;
        dim3 blk(64, 4, 1);
        dim3 grid(xlap > xred ? xlap : xred, ylap + yred, P);
        const float* fine = (l == 0) ? im : (out + off[l]);
        if (l == 0)
            fused_kernel<true><<<grid, blk, 0, stream>>>(fine, out + off[l + 1],
                                                         out + off[l], out + off[l + 2],
                                                         Hc, Wc, ylap);
        else
            fused_kernel<false><<<grid, blk, 0, stream>>>(fine, out + off[l + 1],
                                                          out + off[l], out + off[l + 2],
                                                          Hc, Wc, ylap);
    }

    // lap3: slice3 = slice3 - expand(slice4)
    {
        int Hc = H0 >> 4, Wc = W0 >> 4;   // 64 x 64
        dim3 blk(64, 4, 1);
        dim3 grid((Wc / 4 + 63) / 64, (Hc + 3) / 4, P);
        lap_kernel<<<grid, blk, 0, stream>>>(out + off[3], out + off[4], out + off[3], Hc, Wc);
    }
}